// Round 3
// baseline (275.197 us; speedup 1.0000x reference)
//
#include <hip/hip_runtime.h>
#include <hip/hip_bf16.h>

// AttentionBlock: S=4096, D=1024, H=16, hd=64. fp32 in/out, bf16 MFMA internally.
// ws layout (48 MB):
//   [ 0, 8)MB  Xr : RoPE'd input, bf16 [4096][1024]
//   [ 8,16)MB  Wb : Wq|Wk|Wv|Wo bf16, each [1024][1024] (N x K row-major)
//   [16,24)MB  Q  : bf16 [4096][1024] (pre-scaled by 0.125*log2(e))
//   [24,32)MB  K  : bf16 [4096][1024]
//   [32,40)MB  Vt : bf16 [1024][4096]  == V^T  (row = h*64+d, col = seq)
//   [40,48)MB  Ab : attn out bf16 [4096][1024]
// Softmax: fixed-max. p = exp2(S - 16*log2e) with 0.125*log2e folded into Q.
// Round 9: R8 was jointly LDS/issue-bound at 1 LDS b128 read per MFMA (12 cyc LDS
// vs 8 cyc MFMA). Fix: 64 q-rows/wave (2 strips of 32) -> each K/V frag read feeds
// 2 MFMAs; per-CU frag reads halve (256->128/round). Grid 256 blocks (1/CU,
// 4 waves, 1/SIMD) -- ILP instead of TLP. Row-sum via all-ones-B MFMA into l16
// (C-layout == o-layout: epilogue rcp per reg, zero shuffles). VALU keeps only
// exp/pack/permlane. Predicted wall: trans pipe (~1024 cyc/SIMD/round).

#define SEQ 4096
#define DIM 1024
#define NH 16
#define HD 64

typedef unsigned short u16;
typedef __attribute__((ext_vector_type(4))) u16 u16x4;
typedef __attribute__((ext_vector_type(8))) short s16x8;    // MFMA a/b operand (8 bf16)
typedef __attribute__((ext_vector_type(4))) float f32x4;    // MFMA c/d operand (16x16)
typedef __attribute__((ext_vector_type(16))) float f32x16;  // MFMA c/d operand (32x32)
typedef __attribute__((ext_vector_type(4))) unsigned u32x4;

static __device__ __forceinline__ u16 f2bf(float f) {
  unsigned u = __builtin_bit_cast(unsigned, f);
  u += 0x7FFF + ((u >> 16) & 1);   // RNE
  return (u16)(u >> 16);
}

static __device__ __forceinline__ void glds16(const u16* g, u16* l) {
  __builtin_amdgcn_global_load_lds((const __attribute__((address_space(1))) unsigned*)g,
                                   (__attribute__((address_space(3))) unsigned*)l, 16, 0, 0);
}

static __device__ __forceinline__ float fast_exp2(float x) {
#if __has_builtin(__builtin_amdgcn_exp2f)
  return __builtin_amdgcn_exp2f(x);
#else
  return exp2f(x);
#endif
}

// pack bf16(lo=p0, hi=p1) via byte-perm (RTZ truncation)
static __device__ __forceinline__ unsigned pack_bf(float p0, float p1) {
  return __builtin_amdgcn_perm(__builtin_bit_cast(unsigned, p1),
                               __builtin_bit_cast(unsigned, p0), 0x07060302u);
}

// ---------------- kernel 1: fused RoPE-cast + weight convert ----------------
__global__ __launch_bounds__(256) void prep(const float* __restrict__ x,
                                            const float* __restrict__ cs,
                                            const float* __restrict__ sn,
                                            const float* __restrict__ Wq,
                                            const float* __restrict__ Wk,
                                            const float* __restrict__ Wv,
                                            const float* __restrict__ Wo,
                                            u16* __restrict__ Xr,
                                            u16* __restrict__ Wb) {
  int b = blockIdx.x;
  if (b < 4096) {
    int idx = (b * 256 + threadIdx.x) * 4;
    int d = idx & (DIM - 1);
    f32x4 xv = *(const f32x4*)&x[idx];
    f32x4 cv = *(const f32x4*)&cs[idx];
    f32x4 sv = *(const f32x4*)&sn[idx];
    f32x4 rv;
    if (d < DIM / 2) rv = -*(const f32x4*)&x[idx + DIM / 2];
    else             rv =  *(const f32x4*)&x[idx - DIM / 2];
    f32x4 o = xv * cv + rv * sv;
    u16x4 ov;
    for (int i = 0; i < 4; i++) ov[i] = f2bf(o[i]);
    *(u16x4*)&Xr[idx] = ov;
  } else {
    int idx = ((b - 4096) * 256 + threadIdx.x) * 4;
    const int M = 1 << 20;
    const float* src = (idx < M) ? Wq : (idx < 2 * M) ? Wk : (idx < 3 * M) ? Wv : Wo;
    int off = idx & (M - 1);
    f32x4 v = *(const f32x4*)&src[off];
    u16x4 ov;
    for (int i = 0; i < 4; i++) ov[i] = f2bf(v[i]);
    *(u16x4*)&Wb[idx] = ov;
  }
}

// ---------------- kernel 2: QKV GEMM (C = A @ W^T + b), BK32 dbuf ----------------
__global__ __launch_bounds__(256) void qkv_gemm(const u16* __restrict__ Xr,
                                                const u16* __restrict__ Wb,
                                                const float* __restrict__ bq,
                                                const float* __restrict__ bk,
                                                const float* __restrict__ bv,
                                                u16* __restrict__ Qo,
                                                u16* __restrict__ Ko,
                                                u16* __restrict__ Vt) {
  const int z = blockIdx.z;
  const u16* W = Wb + (size_t)z * DIM * DIM;
  const float* bias = (z == 0) ? bq : (z == 1) ? bk : bv;
  const float scale = (z == 0) ? 0.180336884f : 1.0f;   // 0.125 * log2(e) for Q

  const int m0 = blockIdx.x * 128, n0 = blockIdx.y * 128;
  const int tid = threadIdx.x;
  const int w = tid >> 6, lane = tid & 63, quad = lane >> 4, ln = lane & 15;
  const int rowoff = (w >> 1) * 64, coloff = (w & 1) * 64;

  __shared__ __align__(16) u16 As[2][128 * 32];
  __shared__ __align__(16) u16 Bs[2][128 * 32];

  f32x4 acc[4][4];
  for (int i = 0; i < 4; i++)
    for (int j = 0; j < 4; j++) acc[i][j] = (f32x4){0.f, 0.f, 0.f, 0.f};

  for (int t = 0; t < 2; t++) {
    int i = tid + t * 256, r = i >> 2, p = i & 3, cc = (p ^ (r & 3)) * 8;
    glds16(&Xr[(size_t)(m0 + r) * DIM + cc], As[0] + i * 8);
    glds16(&W[(size_t)(n0 + r) * DIM + cc], Bs[0] + i * 8);
  }

  for (int kt = 0; kt < 32; kt++) {
    __syncthreads();
    if (kt < 31) {
      int k0 = (kt + 1) * 32, nb = (kt + 1) & 1;
      for (int t = 0; t < 2; t++) {
        int i = tid + t * 256, r = i >> 2, p = i & 3, cc = (p ^ (r & 3)) * 8;
        glds16(&Xr[(size_t)(m0 + r) * DIM + k0 + cc], As[nb] + i * 8);
        glds16(&W[(size_t)(n0 + r) * DIM + k0 + cc], Bs[nb] + i * 8);
      }
    }
    int bb = kt & 1;
    s16x8 af[4], bf[4];
    for (int i = 0; i < 4; i++)
      af[i] = *(const s16x8*)&As[bb][(rowoff + i * 16 + ln) * 32 + ((quad ^ (ln & 3)) * 8)];
    for (int j = 0; j < 4; j++)
      bf[j] = *(const s16x8*)&Bs[bb][(coloff + j * 16 + ln) * 32 + ((quad ^ (ln & 3)) * 8)];
    for (int i = 0; i < 4; i++)
      for (int j = 0; j < 4; j++)
        acc[i][j] = __builtin_amdgcn_mfma_f32_16x16x32_bf16(af[i], bf[j], acc[i][j], 0, 0, 0);
  }

  if (z < 2) {
    u16* out = (z == 0) ? Qo : Ko;
    for (int i = 0; i < 4; i++)
      for (int j = 0; j < 4; j++)
        for (int r = 0; r < 4; r++) {
          int row = m0 + rowoff + i * 16 + quad * 4 + r;
          int col = n0 + coloff + j * 16 + ln;
          out[(size_t)row * DIM + col] = f2bf((acc[i][j][r] + bias[col]) * scale);
        }
  } else {
    for (int i = 0; i < 4; i++)
      for (int j = 0; j < 4; j++) {
        int row0 = m0 + rowoff + i * 16 + quad * 4;
        int col = n0 + coloff + j * 16 + ln;
        u16x4 pk;
        for (int r = 0; r < 4; r++) pk[r] = f2bf(acc[i][j][r] + bias[col]);
        *(u16x4*)&Vt[(size_t)col * SEQ + row0] = pk;
      }
  }
}

// ---------------- kernel 3: flash attention, 32x32 MFMA, 64 q-rows/wave ----------------
// 256 blocks = (head, 256 q rows); 4 waves x 64 q (2 strips of 32). kv tiles 64,
// 2 slots/round. Each K/V frag read feeds both strips (2 MFMAs/read). P stays in
// registers (pack_bf + permlane32_swap). Row-sums via all-ones-B MFMA into l16
// whose C-layout matches o -> shuffle-free epilogue.
__global__ __launch_bounds__(256, 1) void attn_kernel(const u16* __restrict__ Q,
                                                      const u16* __restrict__ K,
                                                      const u16* __restrict__ Vt,
                                                      u16* __restrict__ attn) {
  const int b = blockIdx.x;                     // 256 blocks
  const int h = (b & 7) * 2 + ((b >> 3) & 1);   // XCD-aware: 2 heads per XCD
  const int q0 = (b >> 4) * 256;
  const int tid = threadIdx.x;
  const int w = tid >> 6, lane = tid & 63;
  const int l31 = lane & 31, hi = lane >> 5, e3 = l31 & 7;

  // 64KB: K bufs SM[buf*2+slot], V bufs SM[4+buf*2+slot]; Q staged in SM[4..7]
  __shared__ __align__(16) u16 SM[8][4096];

  // stage Q (256x64 = 32KB) into SM[4..7]
  u16* QP = &SM[4][0];
  for (int t = 0; t < 8; t++) {
    int i = tid + t * 256, r = i >> 3, p = i & 7, cc = (p ^ (r & 7)) * 8;
    glds16(&Q[(size_t)(q0 + r) * DIM + h * HD + cc], QP + i * 8);
  }
  __syncthreads();

  // Q B-fragments: lane holds Q[q = w*64+strip*32+l31][k = s*16 + hi*8 + 0..7]
  s16x8 qf[2][4];
#pragma unroll
  for (int strip = 0; strip < 2; strip++) {
    int qrow = w * 64 + strip * 32 + l31;
#pragma unroll
    for (int s = 0; s < 4; s++)
      qf[strip][s] = *(const s16x8*)&QP[qrow * 64 + (((s * 2 + hi) ^ (qrow & 7)) * 8)];
  }
  __syncthreads();   // all waves done reading Q; SM[4..7] free for V staging

  // K/V staging pointers (rows sr and sr+32; (sr+32)&7 == sr&7 so same cc)
  const int sr = tid >> 3, pos = tid & 7;
  const int cc = (pos ^ (sr & 7)) * 8;
  const u16* Kg0 = &K[(size_t)sr * DIM + h * HD + cc];
  const u16* Kg1 = &K[(size_t)(sr + 32) * DIM + h * HD + cc];
  const u16* Vg0 = &Vt[(size_t)(h * HD + sr) * SEQ + cc];
  const u16* Vg1 = &Vt[(size_t)(h * HD + sr + 32) * SEQ + cc];

#pragma unroll
  for (int t = 0; t < 2; t++) {   // prologue: tiles 0,1 -> buf 0
    glds16(Kg0 + (size_t)t * 64 * DIM, SM[t] + tid * 8);
    glds16(Kg1 + (size_t)t * 64 * DIM, SM[t] + (tid + 256) * 8);
    glds16(Vg0 + t * 64, SM[4 + t] + tid * 8);
    glds16(Vg1 + t * 64, SM[4 + t] + (tid + 256) * 8);
  }

  s16x8 onesf;   // all-ones B: every C column = row-sum of A
  for (int j = 0; j < 8; j++) onesf[j] = (short)0x3F80;

  f32x16 o[2][2], l16[2];   // o[strip][db], l16[strip]
#pragma unroll
  for (int strip = 0; strip < 2; strip++) {
    l16[strip] = (f32x16)(0.f);
#pragma unroll
    for (int db = 0; db < 2; db++) o[strip][db] = (f32x16)(0.f);
  }
  const float EC = -23.0831206542f;   // -16*log2(e), as MFMA C-init

  for (int rnd = 0; rnd < 32; rnd++) {
    __syncthreads();     // drains this round's tiles (issued one round ago)
    if (rnd < 31) {      // prefetch next 2 tiles into other buffer
      int nb = (rnd + 1) & 1;
      size_t kt = (size_t)(rnd + 1) * 2;
#pragma unroll
      for (int t = 0; t < 2; t++) {
        glds16(Kg0 + (kt + t) * 64 * DIM, SM[nb * 2 + t] + tid * 8);
        glds16(Kg1 + (kt + t) * 64 * DIM, SM[nb * 2 + t] + (tid + 256) * 8);
        glds16(Vg0 + (kt + t) * 64, SM[4 + nb * 2 + t] + tid * 8);
        glds16(Vg1 + (kt + t) * 64, SM[4 + nb * 2 + t] + (tid + 256) * 8);
      }
    }
    const int bb = rnd & 1;
#pragma unroll
    for (int slot = 0; slot < 2; slot++) {
      const u16* Kt = SM[bb * 2 + slot];
      const u16* Vv = SM[4 + bb * 2 + slot];

      // ---- S^T = K-tile x Q^T: hoist all kf reads, then 16 MFMAs ----
      s16x8 kf[2][4];
#pragma unroll
      for (int s = 0; s < 4; s++)
#pragma unroll
        for (int kb = 0; kb < 2; kb++)
          kf[kb][s] = *(const s16x8*)&Kt[(kb * 32 + l31) * 64 + (((s * 2 + hi) ^ e3) * 8)];

      f32x16 St[2][2];   // [kb][strip]
#pragma unroll
      for (int kb = 0; kb < 2; kb++)
#pragma unroll
        for (int strip = 0; strip < 2; strip++) St[kb][strip] = (f32x16)(EC);

      __builtin_amdgcn_s_setprio(1);
#pragma unroll
      for (int s = 0; s < 4; s++)
#pragma unroll
        for (int kb = 0; kb < 2; kb++)
#pragma unroll
          for (int strip = 0; strip < 2; strip++)
            St[kb][strip] = __builtin_amdgcn_mfma_f32_32x32x16_bf16(kf[kb][s], qf[strip][s],
                                                                    St[kb][strip], 0, 0, 0);
      __builtin_amdgcn_s_setprio(0);

      // hoist all vf reads (land under the exp phase)
      s16x8 vf[2][4];
#pragma unroll
      for (int s = 0; s < 4; s++)
#pragma unroll
        for (int db = 0; db < 2; db++)
          vf[db][s] = *(const s16x8*)&Vv[(db * 32 + l31) * 64 + (((s * 2 + hi) ^ e3) * 8)];

      // ---- per kv-step s: exp+pack+permlane -> PA, then PV MFMAs ----
      // St reg r of [kb][strip]: P^T[kv = kb*32+(r&3)+8*(r>>2)+4*hi][q = strip,l31].
      // PA[strip] for step s: A-operand P[q = l31][kv = s*16 + hi*8 + 0..7].
#pragma unroll
      for (int s = 0; s < 4; s++) {
        const int kb = s >> 1, s0 = (s & 1) * 8;
        s16x8 PAs[2];
#pragma unroll
        for (int strip = 0; strip < 2; strip++) {
          float p[8];
#pragma unroll
          for (int m = 0; m < 8; m++) p[m] = fast_exp2(St[kb][strip][s0 + m]);
          unsigned A = pack_bf(p[0], p[1]);
          unsigned B = pack_bf(p[4], p[5]);
          unsigned C = pack_bf(p[2], p[3]);
          unsigned D = pack_bf(p[6], p[7]);
          asm volatile("v_permlane32_swap_b32 %0, %1" : "+v"(A), "+v"(B));
          asm volatile("v_permlane32_swap_b32 %0, %1" : "+v"(C), "+v"(D));
          u32x4 wd = {A, C, B, D};
          PAs[strip] = __builtin_bit_cast(s16x8, wd);
        }
        __builtin_amdgcn_s_setprio(1);
#pragma unroll
        for (int db = 0; db < 2; db++)
#pragma unroll
          for (int strip = 0; strip < 2; strip++)
            o[strip][db] = __builtin_amdgcn_mfma_f32_32x32x16_bf16(PAs[strip], vf[db][s],
                                                                   o[strip][db], 0, 0, 0);
#pragma unroll
        for (int strip = 0; strip < 2; strip++)
          l16[strip] = __builtin_amdgcn_mfma_f32_32x32x16_bf16(PAs[strip], onesf,
                                                               l16[strip], 0, 0, 0);
        __builtin_amdgcn_s_setprio(0);
      }
    }
  }

  // epilogue: l16[strip][r] is the row-sum for the same q-row as o[strip][*][r]
  // (all columns equal) -> per-register rcp, no shuffles.
#pragma unroll
  for (int strip = 0; strip < 2; strip++)
#pragma unroll
    for (int r = 0; r < 16; r++) {
      float iv = __builtin_amdgcn_rcpf(l16[strip][r]);
      int qr = (r & 3) + 8 * (r >> 2) + 4 * hi;
      int row = q0 + w * 64 + strip * 32 + qr;
#pragma unroll
      for (int db = 0; db < 2; db++)
        attn[(size_t)row * DIM + h * HD + db * 32 + l31] = f2bf(o[strip][db][r] * iv);
    }
}

// ---------------- kernel 4: output GEMM + bias + residual (fp32 out), 128x128 BK32 ----------------
__global__ __launch_bounds__(256) void out_gemm(const u16* __restrict__ A,
                                                const u16* __restrict__ W,
                                                const float* __restrict__ bo,
                                                const float* __restrict__ resid,
                                                float* __restrict__ out) {
  const int m0 = blockIdx.x * 128, n0 = blockIdx.y * 128;
  const int tid = threadIdx.x;
  const int w = tid >> 6, lane = tid & 63, quad = lane >> 4, ln = lane & 15;
  const int rowoff = (w >> 1) * 64, coloff = (w & 1) * 64;

  __shared__ __align__(16) u16 As[2][128 * 32];
  __shared__ __align__(16) u16 Bs[2][128 * 32];

  f32x4 acc[4][4];
  for (int i = 0; i < 4; i++)
    for (int j = 0; j < 4; j++) acc[i][j] = (f32x4){0.f, 0.f, 0.f, 0.f};

  for (int t = 0; t < 2; t++) {
    int i = tid + t * 256, r = i >> 2, p = i & 3, cc = (p ^ (r & 3)) * 8;
    glds16(&A[(size_t)(m0 + r) * DIM + cc], As[0] + i * 8);
    glds16(&W[(size_t)(n0 + r) * DIM + cc], Bs[0] + i * 8);
  }

  for (int kt = 0; kt < 32; kt++) {
    __syncthreads();
    if (kt < 31) {
      int k0 = (kt + 1) * 32, nb = (kt + 1) & 1;
      for (int t = 0; t < 2; t++) {
        int i = tid + t * 256, r = i >> 2, p = i & 3, cc = (p ^ (r & 3)) * 8;
        glds16(&A[(size_t)(m0 + r) * DIM + k0 + cc], As[nb] + i * 8);
        glds16(&W[(size_t)(n0 + r) * DIM + k0 + cc], Bs[nb] + i * 8);
      }
    }
    int bb = kt & 1;
    s16x8 af[4], bf[4];
    for (int i = 0; i < 4; i++)
      af[i] = *(const s16x8*)&As[bb][(rowoff + i * 16 + ln) * 32 + ((quad ^ (ln & 3)) * 8)];
    for (int j = 0; j < 4; j++)
      bf[j] = *(const s16x8*)&Bs[bb][(coloff + j * 16 + ln) * 32 + ((quad ^ (ln & 3)) * 8)];
    for (int i = 0; i < 4; i++)
      for (int j = 0; j < 4; j++)
        acc[i][j] = __builtin_amdgcn_mfma_f32_16x16x32_bf16(af[i], bf[j], acc[i][j], 0, 0, 0);
  }

  for (int i = 0; i < 4; i++)
    for (int j = 0; j < 4; j++)
      for (int r = 0; r < 4; r++) {
        int row = m0 + rowoff + i * 16 + quad * 4 + r;
        int col = n0 + coloff + j * 16 + ln;
        out[(size_t)row * DIM + col] = acc[i][j][r] + bo[col] + resid[(size_t)row * DIM + col];
      }
}

// ---------------- launch ----------------
extern "C" void kernel_launch(void* const* d_in, const int* in_sizes, int n_in,
                              void* d_out, int out_size, void* d_ws, size_t ws_size,
                              hipStream_t stream) {
  const float* cs = (const float*)d_in[0];
  const float* sn = (const float*)d_in[1];
  const float* x  = (const float*)d_in[2];
  const float* Wq = (const float*)d_in[4];  const float* bq = (const float*)d_in[5];
  const float* Wk = (const float*)d_in[6];  const float* bk = (const float*)d_in[7];
  const float* Wv = (const float*)d_in[8];  const float* bv = (const float*)d_in[9];
  const float* Wo = (const float*)d_in[10]; const float* bo = (const float*)d_in[11];
  float* out = (float*)d_out;

  char* ws = (char*)d_ws;
  u16* Xr = (u16*)(ws + (size_t)0);
  u16* Wb = (u16*)(ws + ((size_t)8 << 20));
  u16* Qb = (u16*)(ws + ((size_t)16 << 20));
  u16* Kb = (u16*)(ws + ((size_t)24 << 20));
  u16* Vt = (u16*)(ws + ((size_t)32 << 20));
  u16* Ab = (u16*)(ws + ((size_t)40 << 20));

  prep<<<8192, 256, 0, stream>>>(x, cs, sn, Wq, Wk, Wv, Wo, Xr, Wb);
  qkv_gemm<<<dim3(32, 8, 3), 256, 0, stream>>>(Xr, Wb, bq, bk, bv, Qb, Kb, Vt);
  attn_kernel<<<256, 256, 0, stream>>>(Qb, Kb, Vt, Ab);
  out_gemm<<<dim3(32, 8), 256, 0, stream>>>(Ab, Wb + ((size_t)3 << 20), bo, x, out);
}

// Round 5
// 270.283 us; speedup vs baseline: 1.0182x; 1.0182x over previous
//
#include <hip/hip_runtime.h>
#include <hip/hip_bf16.h>

// AttentionBlock: S=4096, D=1024, H=16, hd=64. fp32 in/out, bf16 MFMA internally.
// ws layout (48 MB):
//   [ 0, 8)MB  Xr : RoPE'd input, bf16 [4096][1024]
//   [ 8,16)MB  Wb : Wq|Wk|Wv|Wo bf16, each [1024][1024] (N x K row-major)
//   [16,24)MB  Q  : bf16 [4096][1024] (pre-scaled by 0.125*log2(e))
//   [24,32)MB  K  : bf16 [4096][1024]
//   [32,40)MB  Vt : bf16 [1024][4096]  == V^T  (row = h*64+d, col = seq)
//   [40,48)MB  Ab : attn out bf16 [4096][1024]
// Softmax: fixed-max. p = exp2(S - 16*log2e) with 0.125*log2e folded into Q.
// Round 11: R10 (kv-split, 128KB LDS) produced NaN; index math re-audited clean,
// prime suspect = first-ever >64KB static LDS (failed launch -> stale Ab = NaN).
// Rebuild kv-split at 64KB: 1 kv-tile(64)/half/round, 32 rounds, Q overlays KS.
// Row-sum moved to VALU scalars (MFMA 40->32 per wave-round, -32 VGPR).
// Two-pass LDS combine of (o, lsum) between kv-halves. 8 waves = 2/SIMD.

#define SEQ 4096
#define DIM 1024
#define NH 16
#define HD 64

typedef unsigned short u16;
typedef __attribute__((ext_vector_type(4))) u16 u16x4;
typedef __attribute__((ext_vector_type(8))) short s16x8;    // MFMA a/b operand (8 bf16)
typedef __attribute__((ext_vector_type(4))) float f32x4;    // MFMA c/d operand (16x16)
typedef __attribute__((ext_vector_type(16))) float f32x16;  // MFMA c/d operand (32x32)
typedef __attribute__((ext_vector_type(4))) unsigned u32x4;

static __device__ __forceinline__ u16 f2bf(float f) {
  unsigned u = __builtin_bit_cast(unsigned, f);
  u += 0x7FFF + ((u >> 16) & 1);   // RNE
  return (u16)(u >> 16);
}

static __device__ __forceinline__ void glds16(const u16* g, u16* l) {
  __builtin_amdgcn_global_load_lds((const __attribute__((address_space(1))) unsigned*)g,
                                   (__attribute__((address_space(3))) unsigned*)l, 16, 0, 0);
}

static __device__ __forceinline__ float fast_exp2(float x) {
#if __has_builtin(__builtin_amdgcn_exp2f)
  return __builtin_amdgcn_exp2f(x);
#else
  return exp2f(x);
#endif
}

// pack bf16(lo=p0, hi=p1) via byte-perm (RTZ truncation)
static __device__ __forceinline__ unsigned pack_bf(float p0, float p1) {
  return __builtin_amdgcn_perm(__builtin_bit_cast(unsigned, p1),
                               __builtin_bit_cast(unsigned, p0), 0x07060302u);
}

// ---------------- kernel 1: fused RoPE-cast + weight convert ----------------
__global__ __launch_bounds__(256) void prep(const float* __restrict__ x,
                                            const float* __restrict__ cs,
                                            const float* __restrict__ sn,
                                            const float* __restrict__ Wq,
                                            const float* __restrict__ Wk,
                                            const float* __restrict__ Wv,
                                            const float* __restrict__ Wo,
                                            u16* __restrict__ Xr,
                                            u16* __restrict__ Wb) {
  int b = blockIdx.x;
  if (b < 4096) {
    int idx = (b * 256 + threadIdx.x) * 4;
    int d = idx & (DIM - 1);
    f32x4 xv = *(const f32x4*)&x[idx];
    f32x4 cv = *(const f32x4*)&cs[idx];
    f32x4 sv = *(const f32x4*)&sn[idx];
    f32x4 rv;
    if (d < DIM / 2) rv = -*(const f32x4*)&x[idx + DIM / 2];
    else             rv =  *(const f32x4*)&x[idx - DIM / 2];
    f32x4 o = xv * cv + rv * sv;
    u16x4 ov;
    for (int i = 0; i < 4; i++) ov[i] = f2bf(o[i]);
    *(u16x4*)&Xr[idx] = ov;
  } else {
    int idx = ((b - 4096) * 256 + threadIdx.x) * 4;
    const int M = 1 << 20;
    const float* src = (idx < M) ? Wq : (idx < 2 * M) ? Wk : (idx < 3 * M) ? Wv : Wo;
    int off = idx & (M - 1);
    f32x4 v = *(const f32x4*)&src[off];
    u16x4 ov;
    for (int i = 0; i < 4; i++) ov[i] = f2bf(v[i]);
    *(u16x4*)&Wb[idx] = ov;
  }
}

// ---------------- kernel 2: QKV GEMM (C = A @ W^T + b), BK32 dbuf ----------------
__global__ __launch_bounds__(256) void qkv_gemm(const u16* __restrict__ Xr,
                                                const u16* __restrict__ Wb,
                                                const float* __restrict__ bq,
                                                const float* __restrict__ bk,
                                                const float* __restrict__ bv,
                                                u16* __restrict__ Qo,
                                                u16* __restrict__ Ko,
                                                u16* __restrict__ Vt) {
  const int z = blockIdx.z;
  const u16* W = Wb + (size_t)z * DIM * DIM;
  const float* bias = (z == 0) ? bq : (z == 1) ? bk : bv;
  const float scale = (z == 0) ? 0.180336884f : 1.0f;   // 0.125 * log2(e) for Q

  const int m0 = blockIdx.x * 128, n0 = blockIdx.y * 128;
  const int tid = threadIdx.x;
  const int w = tid >> 6, lane = tid & 63, quad = lane >> 4, ln = lane & 15;
  const int rowoff = (w >> 1) * 64, coloff = (w & 1) * 64;

  __shared__ __align__(16) u16 As[2][128 * 32];
  __shared__ __align__(16) u16 Bs[2][128 * 32];

  f32x4 acc[4][4];
  for (int i = 0; i < 4; i++)
    for (int j = 0; j < 4; j++) acc[i][j] = (f32x4){0.f, 0.f, 0.f, 0.f};

  for (int t = 0; t < 2; t++) {
    int i = tid + t * 256, r = i >> 2, p = i & 3, cc = (p ^ (r & 3)) * 8;
    glds16(&Xr[(size_t)(m0 + r) * DIM + cc], As[0] + i * 8);
    glds16(&W[(size_t)(n0 + r) * DIM + cc], Bs[0] + i * 8);
  }

  for (int kt = 0; kt < 32; kt++) {
    __syncthreads();
    if (kt < 31) {
      int k0 = (kt + 1) * 32, nb = (kt + 1) & 1;
      for (int t = 0; t < 2; t++) {
        int i = tid + t * 256, r = i >> 2, p = i & 3, cc = (p ^ (r & 3)) * 8;
        glds16(&Xr[(size_t)(m0 + r) * DIM + k0 + cc], As[nb] + i * 8);
        glds16(&W[(size_t)(n0 + r) * DIM + k0 + cc], Bs[nb] + i * 8);
      }
    }
    int bb = kt & 1;
    s16x8 af[4], bf[4];
    for (int i = 0; i < 4; i++)
      af[i] = *(const s16x8*)&As[bb][(rowoff + i * 16 + ln) * 32 + ((quad ^ (ln & 3)) * 8)];
    for (int j = 0; j < 4; j++)
      bf[j] = *(const s16x8*)&Bs[bb][(coloff + j * 16 + ln) * 32 + ((quad ^ (ln & 3)) * 8)];
    for (int i = 0; i < 4; i++)
      for (int j = 0; j < 4; j++)
        acc[i][j] = __builtin_amdgcn_mfma_f32_16x16x32_bf16(af[i], bf[j], acc[i][j], 0, 0, 0);
  }

  if (z < 2) {
    u16* out = (z == 0) ? Qo : Ko;
    for (int i = 0; i < 4; i++)
      for (int j = 0; j < 4; j++)
        for (int r = 0; r < 4; r++) {
          int row = m0 + rowoff + i * 16 + quad * 4 + r;
          int col = n0 + coloff + j * 16 + ln;
          out[(size_t)row * DIM + col] = f2bf((acc[i][j][r] + bias[col]) * scale);
        }
  } else {
    for (int i = 0; i < 4; i++)
      for (int j = 0; j < 4; j++) {
        int row0 = m0 + rowoff + i * 16 + quad * 4;
        int col = n0 + coloff + j * 16 + ln;
        u16x4 pk;
        for (int r = 0; r < 4; r++) pk[r] = f2bf(acc[i][j][r] + bias[col]);
        *(u16x4*)&Vt[(size_t)col * SEQ + row0] = pk;
      }
  }
}

// ---------------- kernel 3: flash attention, 32x32 MFMA, 64 q/wave, kv-split, 64KB LDS ----
// 256 blocks = (head, 256 q rows); 8 waves = (q-strip 0..3 of 64 rows) x (kv-half).
// 32 rounds x 64 kv per half, double-buffered. P register-resident
// (pack_bf + permlane32_swap). Row-sums as VALU scalars lsum[2].
// Halves combined additively via two-pass LDS exchange (fixed-max => no rescale).
__global__ __launch_bounds__(512, 2) void attn_kernel(const u16* __restrict__ Q,
                                                      const u16* __restrict__ K,
                                                      const u16* __restrict__ Vt,
                                                      u16* __restrict__ attn) {
  const int b = blockIdx.x;                     // 256 blocks
  const int h = (b & 7) * 2 + ((b >> 3) & 1);   // XCD-aware: 2 heads per XCD
  const int q0 = (b >> 4) * 256;
  const int tid = threadIdx.x;
  const int w = tid >> 6, lane = tid & 63;
  const int l31 = lane & 31, hi = lane >> 5, e3 = l31 & 7;
  const int qs = w & 3, kh = w >> 2;            // q-strip, kv-half

  __shared__ __align__(16) u16 KS[2][2][4096];  // [half][buf] 32KB; Q staged here first
  __shared__ __align__(16) u16 VS[2][2][4096];  // [half][buf] 32KB

  // stage Q (256x64 = 32KB) into KS (fully consumed before round-0 staging)
  u16* QP = &KS[0][0][0];
  for (int t = 0; t < 4; t++) {
    int i = tid + t * 512, r = i >> 3, p = i & 7, c0 = (p ^ (r & 7)) * 8;
    glds16(&Q[(size_t)(q0 + r) * DIM + h * HD + c0], QP + i * 8);
  }
  __syncthreads();

  // Q B-fragments: lane holds Q[q = qs*64+strip*32+l31][k = s*16 + hi*8 + 0..7]
  s16x8 qf[2][4];
#pragma unroll
  for (int strip = 0; strip < 2; strip++) {
    int qrow = qs * 64 + strip * 32 + l31;
#pragma unroll
    for (int s = 0; s < 4; s++)
      qf[strip][s] = *(const s16x8*)&QP[qrow * 64 + (((s * 2 + hi) ^ (qrow & 7)) * 8)];
  }
  __syncthreads();   // all waves done reading Q; KS free for K staging

  // staging: 512 threads cover one 64x64 tile (8KB) per glds16 call
  const int sr = tid >> 3, pos = tid & 7;
  const int cc = (pos ^ (sr & 7)) * 8;

#define STAGE(rr, buf)                                                                    \
  {                                                                                       \
    _Pragma("unroll") for (int hh = 0; hh < 2; hh++) {                                    \
      int kv0 = hh * 2048 + (rr) * 64;                                                    \
      glds16(&K[(size_t)(kv0 + sr) * DIM + h * HD + cc], &KS[hh][buf][0] + tid * 8);      \
      glds16(&Vt[(size_t)(h * HD + sr) * SEQ + kv0 + cc], &VS[hh][buf][0] + tid * 8);     \
    }                                                                                     \
  }

  STAGE(0, 0);   // prologue: round 0 -> buf 0

  f32x16 o[2][2];   // [strip][db]
#pragma unroll
  for (int strip = 0; strip < 2; strip++)
#pragma unroll
    for (int db = 0; db < 2; db++) o[strip][db] = (f32x16)(0.f);
  float lsum[2] = {0.f, 0.f};
  const float EC = -23.0831206542f;   // -16*log2(e), as MFMA C-init

  for (int rnd = 0; rnd < 32; rnd++) {
    __syncthreads();     // drains this round's tiles (issued one round ago)
    if (rnd < 31) STAGE(rnd + 1, (rnd + 1) & 1);
    const int bb = rnd & 1;
    const u16* Kt = &KS[kh][bb][0];
    const u16* Vv = &VS[kh][bb][0];

    // ---- S^T = K-tile x Q^T: hoist kf reads, then 16 MFMAs ----
    s16x8 kf[2][4];
#pragma unroll
    for (int s = 0; s < 4; s++)
#pragma unroll
      for (int kb = 0; kb < 2; kb++)
        kf[kb][s] = *(const s16x8*)&Kt[(kb * 32 + l31) * 64 + (((s * 2 + hi) ^ e3) * 8)];

    f32x16 St[2][2];   // [kb][strip]
#pragma unroll
    for (int kb = 0; kb < 2; kb++)
#pragma unroll
      for (int strip = 0; strip < 2; strip++) St[kb][strip] = (f32x16)(EC);

    __builtin_amdgcn_s_setprio(1);
#pragma unroll
    for (int s = 0; s < 4; s++)
#pragma unroll
      for (int kb = 0; kb < 2; kb++)
#pragma unroll
        for (int strip = 0; strip < 2; strip++)
          St[kb][strip] = __builtin_amdgcn_mfma_f32_32x32x16_bf16(kf[kb][s], qf[strip][s],
                                                                  St[kb][strip], 0, 0, 0);
    __builtin_amdgcn_s_setprio(0);

    // hoist vf reads (land under the exp phase)
    s16x8 vf[2][4];
#pragma unroll
    for (int s = 0; s < 4; s++)
#pragma unroll
      for (int db = 0; db < 2; db++)
        vf[db][s] = *(const s16x8*)&Vv[(db * 32 + l31) * 64 + (((s * 2 + hi) ^ e3) * 8)];

    // ---- per kv-step s: exp+pack+permlane -> PA, then PV MFMAs ----
    // St reg r of [kb][strip]: P^T[kv = kb*32+(r&3)+8*(r>>2)+4*hi][q = strip,l31].
    // PAs[strip] for step s: A-operand P[q = l31][kv = s*16 + hi*8 + 0..7].
#pragma unroll
    for (int s = 0; s < 4; s++) {
      const int kb = s >> 1, s0 = (s & 1) * 8;
      s16x8 PAs[2];
#pragma unroll
      for (int strip = 0; strip < 2; strip++) {
        float p[8];
#pragma unroll
        for (int m = 0; m < 8; m++) {
          p[m] = fast_exp2(St[kb][strip][s0 + m]);
          lsum[strip] += p[m];
        }
        unsigned A = pack_bf(p[0], p[1]);
        unsigned B = pack_bf(p[4], p[5]);
        unsigned C = pack_bf(p[2], p[3]);
        unsigned D = pack_bf(p[6], p[7]);
        asm volatile("v_permlane32_swap_b32 %0, %1" : "+v"(A), "+v"(B));
        asm volatile("v_permlane32_swap_b32 %0, %1" : "+v"(C), "+v"(D));
        u32x4 wd = {A, C, B, D};
        PAs[strip] = __builtin_bit_cast(s16x8, wd);
      }
      __builtin_amdgcn_s_setprio(1);
#pragma unroll
      for (int db = 0; db < 2; db++)
#pragma unroll
        for (int strip = 0; strip < 2; strip++)
          o[strip][db] = __builtin_amdgcn_mfma_f32_32x32x16_bf16(PAs[strip], vf[db][s],
                                                                 o[strip][db], 0, 0, 0);
      __builtin_amdgcn_s_setprio(0);
    }
  }
#undef STAGE

  // ---- combine kv halves via (now dead) LDS: two passes (one per db) ----
  float* OB = (float*)&KS[0][0][0];   // 32KB scratch: [bi=qs*2+strip][g][lane] f32x4
  float* LB = (float*)&VS[0][0][0];   // 2KB scratch:  [bi][lane] f32
#pragma unroll
  for (int pass = 0; pass < 2; pass++) {
    __syncthreads();
    if (kh == 1) {
#pragma unroll
      for (int strip = 0; strip < 2; strip++) {
        int bi = qs * 2 + strip;
#pragma unroll
        for (int g = 0; g < 4; g++) {
          f32x4 v = {o[strip][pass][g * 4 + 0], o[strip][pass][g * 4 + 1],
                     o[strip][pass][g * 4 + 2], o[strip][pass][g * 4 + 3]};
          *(f32x4*)&OB[((bi * 4 + g) * 64 + lane) * 4] = v;
        }
        if (pass == 0) LB[bi * 64 + lane] = lsum[strip];
      }
    }
    __syncthreads();
    if (kh == 0) {
#pragma unroll
      for (int strip = 0; strip < 2; strip++) {
        int bi = qs * 2 + strip;
#pragma unroll
        for (int g = 0; g < 4; g++) {
          f32x4 v = *(const f32x4*)&OB[((bi * 4 + g) * 64 + lane) * 4];
#pragma unroll
          for (int k = 0; k < 4; k++) o[strip][pass][g * 4 + k] += v[k];
        }
        if (pass == 0) lsum[strip] += LB[bi * 64 + lane];
      }
    }
  }

  // ---- epilogue (kh==0 waves): full row-sum via xor-32, normalize, store ----
  if (kh == 0) {
#pragma unroll
    for (int strip = 0; strip < 2; strip++) {
      float ls = lsum[strip] + __shfl_xor(lsum[strip], 32, 64);
      float iv = __builtin_amdgcn_rcpf(ls);   // lane l: 1/rowsum for q-row l31
#pragma unroll
      for (int r = 0; r < 16; r++) {
        int qr = (r & 3) + 8 * (r >> 2) + 4 * hi;
        float ivr = __shfl(iv, qr, 64);       // row qr's inverse sum
        int row = q0 + qs * 64 + strip * 32 + qr;
#pragma unroll
        for (int db = 0; db < 2; db++)
          attn[(size_t)row * DIM + h * HD + db * 32 + l31] = f2bf(o[strip][db][r] * ivr);
      }
    }
  }
}

// ---------------- kernel 4: output GEMM + bias + residual (fp32 out), 128x128 BK32 ----------------
__global__ __launch_bounds__(256) void out_gemm(const u16* __restrict__ A,
                                                const u16* __restrict__ W,
                                                const float* __restrict__ bo,
                                                const float* __restrict__ resid,
                                                float* __restrict__ out) {
  const int m0 = blockIdx.x * 128, n0 = blockIdx.y * 128;
  const int tid = threadIdx.x;
  const int w = tid >> 6, lane = tid & 63, quad = lane >> 4, ln = lane & 15;
  const int rowoff = (w >> 1) * 64, coloff = (w & 1) * 64;

  __shared__ __align__(16) u16 As[2][128 * 32];
  __shared__ __align__(16) u16 Bs[2][128 * 32];

  f32x4 acc[4][4];
  for (int i = 0; i < 4; i++)
    for (int j = 0; j < 4; j++) acc[i][j] = (f32x4){0.f, 0.f, 0.f, 0.f};

  for (int t = 0; t < 2; t++) {
    int i = tid + t * 256, r = i >> 2, p = i & 3, cc = (p ^ (r & 3)) * 8;
    glds16(&A[(size_t)(m0 + r) * DIM + cc], As[0] + i * 8);
    glds16(&W[(size_t)(n0 + r) * DIM + cc], Bs[0] + i * 8);
  }

  for (int kt = 0; kt < 32; kt++) {
    __syncthreads();
    if (kt < 31) {
      int k0 = (kt + 1) * 32, nb = (kt + 1) & 1;
      for (int t = 0; t < 2; t++) {
        int i = tid + t * 256, r = i >> 2, p = i & 3, cc = (p ^ (r & 3)) * 8;
        glds16(&A[(size_t)(m0 + r) * DIM + k0 + cc], As[nb] + i * 8);
        glds16(&W[(size_t)(n0 + r) * DIM + k0 + cc], Bs[nb] + i * 8);
      }
    }
    int bb = kt & 1;
    s16x8 af[4], bf[4];
    for (int i = 0; i < 4; i++)
      af[i] = *(const s16x8*)&As[bb][(rowoff + i * 16 + ln) * 32 + ((quad ^ (ln & 3)) * 8)];
    for (int j = 0; j < 4; j++)
      bf[j] = *(const s16x8*)&Bs[bb][(coloff + j * 16 + ln) * 32 + ((quad ^ (ln & 3)) * 8)];
    for (int i = 0; i < 4; i++)
      for (int j = 0; j < 4; j++)
        acc[i][j] = __builtin_amdgcn_mfma_f32_16x16x32_bf16(af[i], bf[j], acc[i][j], 0, 0, 0);
  }

  for (int i = 0; i < 4; i++)
    for (int j = 0; j < 4; j++)
      for (int r = 0; r < 4; r++) {
        int row = m0 + rowoff + i * 16 + quad * 4 + r;
        int col = n0 + coloff + j * 16 + ln;
        out[(size_t)row * DIM + col] = acc[i][j][r] + bo[col] + resid[(size_t)row * DIM + col];
      }
}

// ---------------- launch ----------------
extern "C" void kernel_launch(void* const* d_in, const int* in_sizes, int n_in,
                              void* d_out, int out_size, void* d_ws, size_t ws_size,
                              hipStream_t stream) {
  const float* cs = (const float*)d_in[0];
  const float* sn = (const float*)d_in[1];
  const float* x  = (const float*)d_in[2];
  const float* Wq = (const float*)d_in[4];  const float* bq = (const float*)d_in[5];
  const float* Wk = (const float*)d_in[6];  const float* bk = (const float*)d_in[7];
  const float* Wv = (const float*)d_in[8];  const float* bv = (const float*)d_in[9];
  const float* Wo = (const float*)d_in[10]; const float* bo = (const float*)d_in[11];
  float* out = (float*)d_out;

  char* ws = (char*)d_ws;
  u16* Xr = (u16*)(ws + (size_t)0);
  u16* Wb = (u16*)(ws + ((size_t)8 << 20));
  u16* Qb = (u16*)(ws + ((size_t)16 << 20));
  u16* Kb = (u16*)(ws + ((size_t)24 << 20));
  u16* Vt = (u16*)(ws + ((size_t)32 << 20));
  u16* Ab = (u16*)(ws + ((size_t)40 << 20));

  prep<<<8192, 256, 0, stream>>>(x, cs, sn, Wq, Wk, Wv, Wo, Xr, Wb);
  qkv_gemm<<<dim3(32, 8, 3), 256, 0, stream>>>(Xr, Wb, bq, bk, bv, Qb, Kb, Vt);
  attn_kernel<<<256, 512, 0, stream>>>(Qb, Kb, Vt, Ab);
  out_gemm<<<dim3(32, 8), 256, 0, stream>>>(Ab, Wb + ((size_t)3 << 20), bo, x, out);
}

// Round 6
// 267.859 us; speedup vs baseline: 1.0274x; 1.0091x over previous
//
#include <hip/hip_runtime.h>
#include <hip/hip_bf16.h>

// AttentionBlock: S=4096, D=1024, H=16, hd=64. fp32 in/out, bf16 MFMA internally.
// ws layout (48 MB):
//   [ 0, 8)MB  Xr : RoPE'd input, bf16 [4096][1024]
//   [ 8,16)MB  Wb : Wq|Wk|Wv|Wo bf16, each [1024][1024] (N x K row-major)
//   [16,24)MB  Q  : bf16 [4096][1024] (pre-scaled by 0.125*log2(e))
//   [24,32)MB  K  : bf16 [4096][1024]
//   [32,40)MB  Vt : bf16 [1024][4096]  == V^T  (row = h*64+d, col = seq)
//   [40,48)MB  Ab : attn out bf16 [4096][1024]
// Softmax: fixed-max. p = exp2(S - 16*log2e) with 0.125*log2e folded into Q.
// Round 12: R11 counters show MFMA pipe needs ~28us, VALU/trans ~22us, LDS ~20us
// -- wall 88us is pure phase-serialization (QK-MFMA then exp then PV, both
// waves/SIMD barrier-locked in the same phase). Fix: half-tile (32 kv) software
// pipeline inside each wave: QK(kb0) || FINISH(prev kb1), QK(kb1) || FINISH(kb0),
// kb1's vf carried in regs across the round barrier. Register-neutral (St[2][2]
// becomes staggered StA/StB banks; vf reads split early/late). Round 0 peeled so
// the hot loop body is branch-free. Everything else identical to R11 (passed).

#define SEQ 4096
#define DIM 1024
#define NH 16
#define HD 64

typedef unsigned short u16;
typedef __attribute__((ext_vector_type(4))) u16 u16x4;
typedef __attribute__((ext_vector_type(8))) short s16x8;    // MFMA a/b operand (8 bf16)
typedef __attribute__((ext_vector_type(4))) float f32x4;    // MFMA c/d operand (16x16)
typedef __attribute__((ext_vector_type(16))) float f32x16;  // MFMA c/d operand (32x32)
typedef __attribute__((ext_vector_type(4))) unsigned u32x4;

static __device__ __forceinline__ u16 f2bf(float f) {
  unsigned u = __builtin_bit_cast(unsigned, f);
  u += 0x7FFF + ((u >> 16) & 1);   // RNE
  return (u16)(u >> 16);
}

static __device__ __forceinline__ void glds16(const u16* g, u16* l) {
  __builtin_amdgcn_global_load_lds((const __attribute__((address_space(1))) unsigned*)g,
                                   (__attribute__((address_space(3))) unsigned*)l, 16, 0, 0);
}

static __device__ __forceinline__ float fast_exp2(float x) {
#if __has_builtin(__builtin_amdgcn_exp2f)
  return __builtin_amdgcn_exp2f(x);
#else
  return exp2f(x);
#endif
}

// pack bf16(lo=p0, hi=p1) via byte-perm (RTZ truncation)
static __device__ __forceinline__ unsigned pack_bf(float p0, float p1) {
  return __builtin_amdgcn_perm(__builtin_bit_cast(unsigned, p1),
                               __builtin_bit_cast(unsigned, p0), 0x07060302u);
}

// ---------------- kernel 1: fused RoPE-cast + weight convert ----------------
__global__ __launch_bounds__(256) void prep(const float* __restrict__ x,
                                            const float* __restrict__ cs,
                                            const float* __restrict__ sn,
                                            const float* __restrict__ Wq,
                                            const float* __restrict__ Wk,
                                            const float* __restrict__ Wv,
                                            const float* __restrict__ Wo,
                                            u16* __restrict__ Xr,
                                            u16* __restrict__ Wb) {
  int b = blockIdx.x;
  if (b < 4096) {
    int idx = (b * 256 + threadIdx.x) * 4;
    int d = idx & (DIM - 1);
    f32x4 xv = *(const f32x4*)&x[idx];
    f32x4 cv = *(const f32x4*)&cs[idx];
    f32x4 sv = *(const f32x4*)&sn[idx];
    f32x4 rv;
    if (d < DIM / 2) rv = -*(const f32x4*)&x[idx + DIM / 2];
    else             rv =  *(const f32x4*)&x[idx - DIM / 2];
    f32x4 o = xv * cv + rv * sv;
    u16x4 ov;
    for (int i = 0; i < 4; i++) ov[i] = f2bf(o[i]);
    *(u16x4*)&Xr[idx] = ov;
  } else {
    int idx = ((b - 4096) * 256 + threadIdx.x) * 4;
    const int M = 1 << 20;
    const float* src = (idx < M) ? Wq : (idx < 2 * M) ? Wk : (idx < 3 * M) ? Wv : Wo;
    int off = idx & (M - 1);
    f32x4 v = *(const f32x4*)&src[off];
    u16x4 ov;
    for (int i = 0; i < 4; i++) ov[i] = f2bf(v[i]);
    *(u16x4*)&Wb[idx] = ov;
  }
}

// ---------------- kernel 2: QKV GEMM (C = A @ W^T + b), BK32 dbuf ----------------
__global__ __launch_bounds__(256) void qkv_gemm(const u16* __restrict__ Xr,
                                                const u16* __restrict__ Wb,
                                                const float* __restrict__ bq,
                                                const float* __restrict__ bk,
                                                const float* __restrict__ bv,
                                                u16* __restrict__ Qo,
                                                u16* __restrict__ Ko,
                                                u16* __restrict__ Vt) {
  const int z = blockIdx.z;
  const u16* W = Wb + (size_t)z * DIM * DIM;
  const float* bias = (z == 0) ? bq : (z == 1) ? bk : bv;
  const float scale = (z == 0) ? 0.180336884f : 1.0f;   // 0.125 * log2(e) for Q

  const int m0 = blockIdx.x * 128, n0 = blockIdx.y * 128;
  const int tid = threadIdx.x;
  const int w = tid >> 6, lane = tid & 63, quad = lane >> 4, ln = lane & 15;
  const int rowoff = (w >> 1) * 64, coloff = (w & 1) * 64;

  __shared__ __align__(16) u16 As[2][128 * 32];
  __shared__ __align__(16) u16 Bs[2][128 * 32];

  f32x4 acc[4][4];
  for (int i = 0; i < 4; i++)
    for (int j = 0; j < 4; j++) acc[i][j] = (f32x4){0.f, 0.f, 0.f, 0.f};

  for (int t = 0; t < 2; t++) {
    int i = tid + t * 256, r = i >> 2, p = i & 3, cc = (p ^ (r & 3)) * 8;
    glds16(&Xr[(size_t)(m0 + r) * DIM + cc], As[0] + i * 8);
    glds16(&W[(size_t)(n0 + r) * DIM + cc], Bs[0] + i * 8);
  }

  for (int kt = 0; kt < 32; kt++) {
    __syncthreads();
    if (kt < 31) {
      int k0 = (kt + 1) * 32, nb = (kt + 1) & 1;
      for (int t = 0; t < 2; t++) {
        int i = tid + t * 256, r = i >> 2, p = i & 3, cc = (p ^ (r & 3)) * 8;
        glds16(&Xr[(size_t)(m0 + r) * DIM + k0 + cc], As[nb] + i * 8);
        glds16(&W[(size_t)(n0 + r) * DIM + k0 + cc], Bs[nb] + i * 8);
      }
    }
    int bb = kt & 1;
    s16x8 af[4], bf[4];
    for (int i = 0; i < 4; i++)
      af[i] = *(const s16x8*)&As[bb][(rowoff + i * 16 + ln) * 32 + ((quad ^ (ln & 3)) * 8)];
    for (int j = 0; j < 4; j++)
      bf[j] = *(const s16x8*)&Bs[bb][(coloff + j * 16 + ln) * 32 + ((quad ^ (ln & 3)) * 8)];
    for (int i = 0; i < 4; i++)
      for (int j = 0; j < 4; j++)
        acc[i][j] = __builtin_amdgcn_mfma_f32_16x16x32_bf16(af[i], bf[j], acc[i][j], 0, 0, 0);
  }

  if (z < 2) {
    u16* out = (z == 0) ? Qo : Ko;
    for (int i = 0; i < 4; i++)
      for (int j = 0; j < 4; j++)
        for (int r = 0; r < 4; r++) {
          int row = m0 + rowoff + i * 16 + quad * 4 + r;
          int col = n0 + coloff + j * 16 + ln;
          out[(size_t)row * DIM + col] = f2bf((acc[i][j][r] + bias[col]) * scale);
        }
  } else {
    for (int i = 0; i < 4; i++)
      for (int j = 0; j < 4; j++) {
        int row0 = m0 + rowoff + i * 16 + quad * 4;
        int col = n0 + coloff + j * 16 + ln;
        u16x4 pk;
        for (int r = 0; r < 4; r++) pk[r] = f2bf(acc[i][j][r] + bias[col]);
        *(u16x4*)&Vt[(size_t)col * SEQ + row0] = pk;
      }
  }
}

// ---------------- kernel 3: flash attention, 32x32 MFMA, kv-split, half-tile pipelined ----
// 256 blocks = (head, 256 q rows); 8 waves = (q-strip 0..3 of 64 rows) x (kv-half).
// 32 rounds x 64 kv per half, double-buffered. Half-tile (32 kv) software pipeline:
// QK of one half overlaps softmax+PV (FINISH) of the previous half, in-wave.
// P register-resident (pack_bf + permlane32_swap). Row-sums as VALU scalars.
// Halves combined additively via two-pass LDS exchange (fixed-max => no rescale).
__global__ __launch_bounds__(512, 2) void attn_kernel(const u16* __restrict__ Q,
                                                      const u16* __restrict__ K,
                                                      const u16* __restrict__ Vt,
                                                      u16* __restrict__ attn) {
  const int b = blockIdx.x;                     // 256 blocks
  const int h = (b & 7) * 2 + ((b >> 3) & 1);   // XCD-aware: 2 heads per XCD
  const int q0 = (b >> 4) * 256;
  const int tid = threadIdx.x;
  const int w = tid >> 6, lane = tid & 63;
  const int l31 = lane & 31, hi = lane >> 5, e3 = l31 & 7;
  const int qs = w & 3, kh = w >> 2;            // q-strip, kv-half

  __shared__ __align__(16) u16 KS[2][2][4096];  // [half][buf] 32KB; Q staged here first
  __shared__ __align__(16) u16 VS[2][2][4096];  // [half][buf] 32KB

  // stage Q (256x64 = 32KB) into KS (fully consumed before round-0 staging)
  u16* QP = &KS[0][0][0];
  for (int t = 0; t < 4; t++) {
    int i = tid + t * 512, r = i >> 3, p = i & 7, c0 = (p ^ (r & 7)) * 8;
    glds16(&Q[(size_t)(q0 + r) * DIM + h * HD + c0], QP + i * 8);
  }
  __syncthreads();

  // Q B-fragments: lane holds Q[q = qs*64+strip*32+l31][k = s*16 + hi*8 + 0..7]
  s16x8 qf[2][4];
#pragma unroll
  for (int strip = 0; strip < 2; strip++) {
    int qrow = qs * 64 + strip * 32 + l31;
#pragma unroll
    for (int s = 0; s < 4; s++)
      qf[strip][s] = *(const s16x8*)&QP[qrow * 64 + (((s * 2 + hi) ^ (qrow & 7)) * 8)];
  }
  __syncthreads();   // all waves done reading Q; KS free for K staging

  // staging: 512 threads cover one 64x64 tile (8KB) per glds16 call
  const int sr = tid >> 3, pos = tid & 7;
  const int cc = (pos ^ (sr & 7)) * 8;

#define STAGE(rr, buf)                                                                    \
  {                                                                                       \
    _Pragma("unroll") for (int hh = 0; hh < 2; hh++) {                                    \
      int kv0 = hh * 2048 + (rr) * 64;                                                    \
      glds16(&K[(size_t)(kv0 + sr) * DIM + h * HD + cc], &KS[hh][buf][0] + tid * 8);      \
      glds16(&Vt[(size_t)(h * HD + sr) * SEQ + kv0 + cc], &VS[hh][buf][0] + tid * 8);     \
    }                                                                                     \
  }

  STAGE(0, 0);   // prologue: round 0 -> buf 0

  f32x16 o[2][2];   // [strip][db]
#pragma unroll
  for (int strip = 0; strip < 2; strip++)
#pragma unroll
    for (int db = 0; db < 2; db++) o[strip][db] = (f32x16)(0.f);
  float lsum[2] = {0.f, 0.f};
  const float EC = -23.0831206542f;   // -16*log2(e), as MFMA C-init

  f32x16 StA[2], StB[2];        // St banks [strip]; StB carried across rounds
  s16x8 vA[2], vB[2];           // current tile kb0 V-frags [db] (s=0,1)
  s16x8 vpA[2], vpB[2];         // prev tile kb1 V-frags [db] (s=2,3), carried

  // QK for one half-tile kb into bank Stb (8 MFMAs)
#define QKHALF(Stb, kb)                                                                   \
  {                                                                                       \
    Stb[0] = (f32x16)(EC);                                                                \
    Stb[1] = (f32x16)(EC);                                                                \
    __builtin_amdgcn_s_setprio(1);                                                        \
    _Pragma("unroll") for (int s = 0; s < 4; s++)                                         \
      _Pragma("unroll") for (int strip = 0; strip < 2; strip++)                           \
        Stb[strip] = __builtin_amdgcn_mfma_f32_32x32x16_bf16(kf[kb][s], qf[strip][s],     \
                                                             Stb[strip], 0, 0, 0);        \
    __builtin_amdgcn_s_setprio(0);                                                        \
  }

  // finish one half-tile: exp + pack + permlane -> PA, then 8 PV MFMAs + lsum.
  // St bank reg r of [strip]: P^T[kv_local = (r&3)+8*(r>>2)+4*hi][q = strip,l31];
  // sl=0 -> regs 0..7 (kv_local 0..15), sl=1 -> regs 8..15.
#define FINISH(Stb, v0, v1)                                                               \
  {                                                                                       \
    _Pragma("unroll") for (int sl = 0; sl < 2; sl++) {                                    \
      s16x8 PAs[2];                                                                       \
      _Pragma("unroll") for (int strip = 0; strip < 2; strip++) {                         \
        float p[8];                                                                       \
        _Pragma("unroll") for (int m = 0; m < 8; m++) {                                   \
          p[m] = fast_exp2(Stb[strip][sl * 8 + m]);                                       \
          lsum[strip] += p[m];                                                            \
        }                                                                                 \
        unsigned A = pack_bf(p[0], p[1]);                                                 \
        unsigned B = pack_bf(p[4], p[5]);                                                 \
        unsigned C = pack_bf(p[2], p[3]);                                                 \
        unsigned D = pack_bf(p[6], p[7]);                                                 \
        asm volatile("v_permlane32_swap_b32 %0, %1" : "+v"(A), "+v"(B));                  \
        asm volatile("v_permlane32_swap_b32 %0, %1" : "+v"(C), "+v"(D));                  \
        u32x4 wd = {A, C, B, D};                                                          \
        PAs[strip] = __builtin_bit_cast(s16x8, wd);                                       \
      }                                                                                   \
      __builtin_amdgcn_s_setprio(1);                                                      \
      _Pragma("unroll") for (int db = 0; db < 2; db++)                                    \
        _Pragma("unroll") for (int strip = 0; strip < 2; strip++)                         \
          o[strip][db] = __builtin_amdgcn_mfma_f32_32x32x16_bf16(                         \
              PAs[strip], (sl == 0) ? (v0)[db] : (v1)[db], o[strip][db], 0, 0, 0);        \
      __builtin_amdgcn_s_setprio(0);                                                      \
    }                                                                                     \
  }

#define READKF()                                                                          \
    _Pragma("unroll") for (int s = 0; s < 4; s++)                                         \
      _Pragma("unroll") for (int kb = 0; kb < 2; kb++)                                    \
        kf[kb][s] = *(const s16x8*)&Kt[(kb * 32 + l31) * 64 + (((s * 2 + hi) ^ e3) * 8)];
#define READV(dst, s)                                                                     \
    _Pragma("unroll") for (int db = 0; db < 2; db++)                                      \
      dst[db] = *(const s16x8*)&Vv[(db * 32 + l31) * 64 + ((((s) * 2 + hi) ^ e3) * 8)];

  // ---- peeled round 0 (no previous half-tile to finish) ----
  {
    __syncthreads();
    STAGE(1, 1);
    const u16* Kt = &KS[kh][0][0];
    const u16* Vv = &VS[kh][0][0];
    s16x8 kf[2][4];
    READKF();
    QKHALF(StA, 0);
    READV(vA, 0);
    READV(vB, 1);
    QKHALF(StB, 1);
    FINISH(StA, vA, vB);
    READV(vpA, 2);
    READV(vpB, 3);
  }

  // ---- main loop: rounds 1..31, branch-free hot body ----
  for (int rnd = 1; rnd < 32; rnd++) {
    __syncthreads();     // drains this round's tiles (issued one round ago)
    if (rnd < 31) STAGE(rnd + 1, (rnd + 1) & 1);
    const int bb = rnd & 1;
    const u16* Kt = &KS[kh][bb][0];
    const u16* Vv = &VS[kh][bb][0];

    s16x8 kf[2][4];
    READKF();
    QKHALF(StA, 0);            // MFMA stream for this tile's kb0 ...
    FINISH(StB, vpA, vpB);     // ... overlapped with prev tile kb1 softmax+PV
    READV(vA, 0);
    READV(vB, 1);
    QKHALF(StB, 1);            // MFMA stream for kb1 ...
    FINISH(StA, vA, vB);       // ... overlapped with kb0 softmax+PV
    READV(vpA, 2);             // carry kb1 V-frags across the barrier
    READV(vpB, 3);
  }
  FINISH(StB, vpA, vpB);       // tail: tile 31's kb1
#undef STAGE
#undef QKHALF
#undef FINISH
#undef READKF
#undef READV

  // ---- combine kv halves via (now dead) LDS: two passes (one per db) ----
  float* OB = (float*)&KS[0][0][0];   // 32KB scratch: [bi=qs*2+strip][g][lane] f32x4
  float* LB = (float*)&VS[0][0][0];   // 2KB scratch:  [bi][lane] f32
#pragma unroll
  for (int pass = 0; pass < 2; pass++) {
    __syncthreads();
    if (kh == 1) {
#pragma unroll
      for (int strip = 0; strip < 2; strip++) {
        int bi = qs * 2 + strip;
#pragma unroll
        for (int g = 0; g < 4; g++) {
          f32x4 v = {o[strip][pass][g * 4 + 0], o[strip][pass][g * 4 + 1],
                     o[strip][pass][g * 4 + 2], o[strip][pass][g * 4 + 3]};
          *(f32x4*)&OB[((bi * 4 + g) * 64 + lane) * 4] = v;
        }
        if (pass == 0) LB[bi * 64 + lane] = lsum[strip];
      }
    }
    __syncthreads();
    if (kh == 0) {
#pragma unroll
      for (int strip = 0; strip < 2; strip++) {
        int bi = qs * 2 + strip;
#pragma unroll
        for (int g = 0; g < 4; g++) {
          f32x4 v = *(const f32x4*)&OB[((bi * 4 + g) * 64 + lane) * 4];
#pragma unroll
          for (int k = 0; k < 4; k++) o[strip][pass][g * 4 + k] += v[k];
        }
        if (pass == 0) lsum[strip] += LB[bi * 64 + lane];
      }
    }
  }

  // ---- epilogue (kh==0 waves): full row-sum via xor-32, normalize, store ----
  if (kh == 0) {
#pragma unroll
    for (int strip = 0; strip < 2; strip++) {
      float ls = lsum[strip] + __shfl_xor(lsum[strip], 32, 64);
      float iv = __builtin_amdgcn_rcpf(ls);   // lane l: 1/rowsum for q-row l31
#pragma unroll
      for (int r = 0; r < 16; r++) {
        int qr = (r & 3) + 8 * (r >> 2) + 4 * hi;
        float ivr = __shfl(iv, qr, 64);       // row qr's inverse sum
        int row = q0 + qs * 64 + strip * 32 + qr;
#pragma unroll
        for (int db = 0; db < 2; db++)
          attn[(size_t)row * DIM + h * HD + db * 32 + l31] = f2bf(o[strip][db][r] * ivr);
      }
    }
  }
}

// ---------------- kernel 4: output GEMM + bias + residual (fp32 out), 128x128 BK32 ----------------
__global__ __launch_bounds__(256) void out_gemm(const u16* __restrict__ A,
                                                const u16* __restrict__ W,
                                                const float* __restrict__ bo,
                                                const float* __restrict__ resid,
                                                float* __restrict__ out) {
  const int m0 = blockIdx.x * 128, n0 = blockIdx.y * 128;
  const int tid = threadIdx.x;
  const int w = tid >> 6, lane = tid & 63, quad = lane >> 4, ln = lane & 15;
  const int rowoff = (w >> 1) * 64, coloff = (w & 1) * 64;

  __shared__ __align__(16) u16 As[2][128 * 32];
  __shared__ __align__(16) u16 Bs[2][128 * 32];

  f32x4 acc[4][4];
  for (int i = 0; i < 4; i++)
    for (int j = 0; j < 4; j++) acc[i][j] = (f32x4){0.f, 0.f, 0.f, 0.f};

  for (int t = 0; t < 2; t++) {
    int i = tid + t * 256, r = i >> 2, p = i & 3, cc = (p ^ (r & 3)) * 8;
    glds16(&A[(size_t)(m0 + r) * DIM + cc], As[0] + i * 8);
    glds16(&W[(size_t)(n0 + r) * DIM + cc], Bs[0] + i * 8);
  }

  for (int kt = 0; kt < 32; kt++) {
    __syncthreads();
    if (kt < 31) {
      int k0 = (kt + 1) * 32, nb = (kt + 1) & 1;
      for (int t = 0; t < 2; t++) {
        int i = tid + t * 256, r = i >> 2, p = i & 3, cc = (p ^ (r & 3)) * 8;
        glds16(&A[(size_t)(m0 + r) * DIM + k0 + cc], As[nb] + i * 8);
        glds16(&W[(size_t)(n0 + r) * DIM + k0 + cc], Bs[nb] + i * 8);
      }
    }
    int bb = kt & 1;
    s16x8 af[4], bf[4];
    for (int i = 0; i < 4; i++)
      af[i] = *(const s16x8*)&As[bb][(rowoff + i * 16 + ln) * 32 + ((quad ^ (ln & 3)) * 8)];
    for (int j = 0; j < 4; j++)
      bf[j] = *(const s16x8*)&Bs[bb][(coloff + j * 16 + ln) * 32 + ((quad ^ (ln & 3)) * 8)];
    for (int i = 0; i < 4; i++)
      for (int j = 0; j < 4; j++)
        acc[i][j] = __builtin_amdgcn_mfma_f32_16x16x32_bf16(af[i], bf[j], acc[i][j], 0, 0, 0);
  }

  for (int i = 0; i < 4; i++)
    for (int j = 0; j < 4; j++)
      for (int r = 0; r < 4; r++) {
        int row = m0 + rowoff + i * 16 + quad * 4 + r;
        int col = n0 + coloff + j * 16 + ln;
        out[(size_t)row * DIM + col] = acc[i][j][r] + bo[col] + resid[(size_t)row * DIM + col];
      }
}

// ---------------- launch ----------------
extern "C" void kernel_launch(void* const* d_in, const int* in_sizes, int n_in,
                              void* d_out, int out_size, void* d_ws, size_t ws_size,
                              hipStream_t stream) {
  const float* cs = (const float*)d_in[0];
  const float* sn = (const float*)d_in[1];
  const float* x  = (const float*)d_in[2];
  const float* Wq = (const float*)d_in[4];  const float* bq = (const float*)d_in[5];
  const float* Wk = (const float*)d_in[6];  const float* bk = (const float*)d_in[7];
  const float* Wv = (const float*)d_in[8];  const float* bv = (const float*)d_in[9];
  const float* Wo = (const float*)d_in[10]; const float* bo = (const float*)d_in[11];
  float* out = (float*)d_out;

  char* ws = (char*)d_ws;
  u16* Xr = (u16*)(ws + (size_t)0);
  u16* Wb = (u16*)(ws + ((size_t)8 << 20));
  u16* Qb = (u16*)(ws + ((size_t)16 << 20));
  u16* Kb = (u16*)(ws + ((size_t)24 << 20));
  u16* Vt = (u16*)(ws + ((size_t)32 << 20));
  u16* Ab = (u16*)(ws + ((size_t)40 << 20));

  prep<<<8192, 256, 0, stream>>>(x, cs, sn, Wq, Wk, Wv, Wo, Xr, Wb);
  qkv_gemm<<<dim3(32, 8, 3), 256, 0, stream>>>(Xr, Wb, bq, bk, bv, Qb, Kb, Vt);
  attn_kernel<<<256, 512, 0, stream>>>(Qb, Kb, Vt, Ab);
  out_gemm<<<dim3(32, 8), 256, 0, stream>>>(Ab, Wb + ((size_t)3 << 20), bo, x, out);
}